// Round 8
// baseline (771.740 us; speedup 1.0000x reference)
//
#include <hip/hip_runtime.h>
#include <hip/hip_cooperative_groups.h>
#include <cmath>

// ---------------- problem constants ----------------
#define FEAT  192
#define CINCH 384          // CIN
#define CGATE 768
#define BATCH 16
#define HH    64
#define WW    64
#define NP    (BATCH*HH*WW)   // 65536 flattened (b,y,w)
#define KI2S  768             // 384 ic * 2 live taps
#define KS2S  576             // 192 feat * 3 taps
#define NBLK  192             // scan blocks: 16 batches x 12 f-chunks
#define SCANT 512             // scan threads: 8 waves

using bf16   = __bf16;
using bf16x8 = __attribute__((ext_vector_type(8))) __bf16;
using bf16x4 = __attribute__((ext_vector_type(4))) __bf16;
using f32x4  = __attribute__((ext_vector_type(4))) float;
typedef unsigned long long u64;

// ---------------------------------------------------------------
// IC-coherent accessors: relaxed agent-scope atomics -> plain
// global_load/store with sc0/sc1 (bypass L1/L2, coherent at Infinity
// Cache). No cache-wide wbl2/inv on the per-row path. Visibility:
// sc1 store completion (vmcnt==0 via __syncthreads drain) => at IC.
// ---------------------------------------------------------------
__device__ __forceinline__ void ic_store64(u64* p, u64 v) {
    __hip_atomic_store(p, v, __ATOMIC_RELAXED, __HIP_MEMORY_SCOPE_AGENT);
}
__device__ __forceinline__ u64 ic_load64(const u64* p) {
    return __hip_atomic_load(p, __ATOMIC_RELAXED, __HIP_MEMORY_SCOPE_AGENT);
}
__device__ __forceinline__ void ic_store32(unsigned* p, unsigned v) {
    __hip_atomic_store(p, v, __ATOMIC_RELAXED, __HIP_MEMORY_SCOPE_AGENT);
}
__device__ __forceinline__ unsigned ic_load32(const unsigned* p) {
    return __hip_atomic_load(p, __ATOMIC_RELAXED, __HIP_MEMORY_SCOPE_AGENT);
}
__device__ __forceinline__ void ic_store16(bf16* p, bf16 h) {
    union { bf16 h; unsigned short u; } cv; cv.h = h;
    __hip_atomic_store((unsigned short*)p, cv.u, __ATOMIC_RELAXED, __HIP_MEMORY_SCOPE_AGENT);
}
__device__ __forceinline__ float ic_load_bf16(const bf16* p) {
    union { unsigned short u; bf16 h; } cv;
    cv.u = __hip_atomic_load((const unsigned short*)p, __ATOMIC_RELAXED, __HIP_MEMORY_SCOPE_AGENT);
    return (float)cv.h;
}

__device__ __forceinline__ float sigm_fast(float v) {
    return __builtin_amdgcn_rcpf(1.f + __expf(-v));
}
__device__ __forceinline__ float tanh_fast(float v) {
    return 1.f - 2.f * __builtin_amdgcn_rcpf(1.f + __expf(2.f * v));
}

// ============================================================
// Pack weights (layouts unchanged, verified). Also zeroes the zp page.
// ============================================================
__global__ void pack_weights(const float* __restrict__ wi, const float* __restrict__ ws,
                             const float* __restrict__ wk,
                             bf16* __restrict__ WpA, bf16* __restrict__ WpS,
                             bf16* __restrict__ WpK, bf16* __restrict__ zp) {
    int tid = blockIdx.x * 256 + threadIdx.x;
    int stride = gridDim.x * 256;
    for (int idx = tid; idx < 512; idx += stride) zp[idx] = (bf16)0.f;
    for (int idx = tid; idx < CGATE * KI2S; idx += stride) {
        int cp = idx / KI2S, k = idx % KI2S;
        int q = cp / 192, r = cp % 192, g = r / 64, f = r % 64;
        int c = g * 256 + q * 64 + f;             // original (pre-shuffle) out channel
        float v;
        if (k < CINCH) {
            v = wi[(c * CINCH + k) * 3 + 0];      // tap0 (pairs with x[w-1])
        } else {
            int ic = k - CINCH;                   // tap1 (center, causal mask; pairs x[w])
            v = (g >= ic / 128) ? wi[(c * CINCH + ic) * 3 + 1] : 0.f;
        }
        WpA[idx] = (bf16)v;
    }
    for (int idx = tid; idx < CGATE * KS2S; idx += stride) {
        int oc = idx / KS2S, k = idx % KS2S;
        int t = k / FEAT, f = k % FEAT;
        WpS[idx] = (bf16)ws[(oc * FEAT + f) * 3 + t];
    }
    for (int idx = tid; idx < CINCH * FEAT; idx += stride) {
        int co = idx / FEAT, f = idx % FEAT;
        WpK[idx] = (co / 128 >= f / 64) ? (bf16)wk[idx] : (bf16)0.f;
    }
}

// ============================================================
// Pack x (fp32 NCHW) -> Xc bf16 [p=(b,y,w)][ic 0..384)  (non-redundant;
// the two conv taps are reconstructed at B-staging time via p / p-1).
// ============================================================
__global__ void pack_xc(const float* __restrict__ x, bf16* __restrict__ Xc) {
    __shared__ float tile[64][65];
    int b = blockIdx.x >> 6, y = blockIdx.x & 63;
    const float* xb = x + ((size_t)b * CINCH * HH + y) * WW;
    bf16* Xrow = Xc + (size_t)((b * HH + y) * WW) * CINCH;
    for (int ic0 = 0; ic0 < CINCH; ic0 += 64) {
        for (int rep = 0; rep < 16; ++rep) {
            int idx = rep * 256 + threadIdx.x;
            int i = idx >> 6, w = idx & 63;
            tile[i][w] = xb[(size_t)(ic0 + i) * (HH * WW) + w];
        }
        __syncthreads();
        for (int rep = 0; rep < 16; ++rep) {
            int idx = rep * 256 + threadIdx.x;
            int w = idx >> 6, i = idx & 63;
            Xrow[(size_t)w * CINCH + ic0 + i] = (bf16)tile[i][w];
        }
        __syncthreads();
    }
}

// ============================================================
// Cooperative row scan with y-ordered FUSED i2s GEMM.
// 192 blocks x 512 threads. Block (b,j) owns i2s tiles t = j + 12n
// (n=0..15); tile t: m0=(t%6)*128 c'-rows, yh=t/6 (x-rows 2yh,2yh+1).
// Schedule: tile 0 in prologue; tile n during rows 4n-4..4n-1 (3 K-iters
// per row), epilogue+flag at row 4n-1. Output goes to an IC-coherent
// 8-row/batch ring (Hring); consumers ballot-poll per-block monotone
// tile-count flags, then sc1-load gate biases (1 row lookahead).
// Ring safety: producer lead <= 4 rows < 8-slot ring; block skew <= 1 row
// (h-barrier). Deadlock-free: h-flag precedes chunk precedes g-poll.
// ============================================================
__global__ __launch_bounds__(SCANT, 2) void scan_kernel(
    const bf16* __restrict__ WpA,    // [768][768] i2s weights
    const bf16* __restrict__ Ws2s,   // [768][576]
    const bf16* __restrict__ Wskip,  // [384][192]
    const bf16* __restrict__ Xc,     // [65536][384]
    const bf16* __restrict__ zp,     // 1KB zero page
    const float* __restrict__ x,
    const float* __restrict__ b_skip,
    float* __restrict__ out,
    bf16* __restrict__ hg,           // [3][16][66*192]
    unsigned* __restrict__ cnt,      // [0..511] h-flags, [512..1023] g-flags
    bf16* __restrict__ Hring) {      // [768][16][8][64]
    cooperative_groups::grid_group grid = cooperative_groups::this_grid();
    __shared__ __align__(16) bf16 hlds[66 * 200];   // staged full h row (halo idx)
    __shared__ __align__(16) bf16 hnew[64 * 20];    // own 16f slice of h(y)
    __shared__ __align__(16) bf16 As2[128 * 64];    // i2s A tile
    __shared__ __align__(16) bf16 Bs2[128 * 64];    // i2s B tile
    const int bid = blockIdx.x;
    const int b = (bid & 7) * 2 + (bid / 96);   // same-batch blocks share bid%8
    const int j = (bid >> 3) % 12;
    const int tid = threadIdx.x, lane = tid & 63, wid = tid >> 6;
    const int quad = lane >> 4, col = lane & 15;
    const int wh = wid & 3;                     // h-GEMM m-slice role
    const int wn = wid >> 2;                    // h-GEMM n-half
    const int mq = wid & 1, nq = wid >> 1;      // i2s GEMM wave roles

    // ---- init: zero hg + flags + hlds (h(-1) = 0) ----
    {
        const int total = 3 * 16 * 66 * 192 / 2;   // dwords
        for (int i = bid * SCANT + tid; i < total; i += NBLK * SCANT)
            ((unsigned*)hg)[i] = 0u;
        if (tid < 32) cnt[(bid % 16) * 32 + tid] = 0u;
        if (tid >= 64 && tid < 96) cnt[512 + (bid % 16) * 32 + (tid - 64)] = 0u;
        for (int i = tid; i < 66 * 100; i += SCANT) ((unsigned*)hlds)[i] = 0u;
    }
    // persistent A fragments for h-GEMMs
    bf16x8 Ag[18];
    {
        int f = 16 * j + wh * 4 + (col >> 2), q = col & 3;
        const bf16* Arow = Ws2s + (size_t)(q * 192 + f) * KS2S + quad * 8;
        for (int kc = 0; kc < 18; ++kc) Ag[kc] = *(const bf16x8*)(Arow + kc * 32);
    }
    bf16x8 Ak[6];
    const int mtk = wid & 1, ntk = wid >> 1;    // skip: co-half x w-quarter
    {
        int co = 32 * j + mtk * 16 + col;
        const bf16* Krow = Wskip + (size_t)co * FEAT + quad * 8;
        for (int kc = 0; kc < 6; ++kc) Ak[kc] = *(const bf16x8*)(Krow + kc * 32);
    }
    const int fmine = 16 * j + wh * 4 + quad;
    const int lf = wh * 4 + quad;               // local feature 0..15
    float cstate[2] = {0.f, 0.f};
    unsigned* myflags = cnt + b * 32;           // h flags (12)
    unsigned* gflags  = cnt + 512 + b * 32;     // gemm tile-count flags (12)
    grid.sync();   // init visibility

// ---- i2s GEMM helpers (structure verbatim from verified gemm_i2s,
//      adapted to 8 waves: per-wave 64m x 32n) ----
#define GSTAGE(M0, P0, K0) do {                                                    \
    _Pragma("unroll")                                                              \
    for (int r_ = 0; r_ < 2; ++r_) {                                               \
        int L_ = r_ * 512 + tid;                                                   \
        int row_ = L_ >> 3, slot_ = L_ & 7;                                        \
        int c_ = slot_ ^ (row_ & 7);                                               \
        const bf16* srcA = &WpA[(size_t)((M0) + row_) * KI2S + (K0) + c_ * 8];     \
        const bf16* srcB;                                                          \
        if ((K0) < 384) {                                                          \
            srcB = ((row_ & 63) == 0) ? (zp + c_ * 8)                              \
                 : &Xc[(size_t)((P0) + row_ - 1) * CINCH + (K0) + c_ * 8];         \
        } else {                                                                   \
            srcB = &Xc[(size_t)((P0) + row_) * CINCH + (K0) - 384 + c_ * 8];       \
        }                                                                          \
        bf16* dA = As2 + (size_t)(r_ * 512 + wid * 64) * 8;                        \
        bf16* dB = Bs2 + (size_t)(r_ * 512 + wid * 64) * 8;                        \
        __builtin_amdgcn_global_load_lds(                                          \
            (const __attribute__((address_space(1))) void*)srcA,                   \
            (__attribute__((address_space(3))) void*)dA, 16, 0, 0);                \
        __builtin_amdgcn_global_load_lds(                                          \
            (const __attribute__((address_space(1))) void*)srcB,                   \
            (__attribute__((address_space(3))) void*)dB, 16, 0, 0);                \
    }                                                                              \
} while (0)

#define GMFMA(ACC) do {                                                            \
    _Pragma("unroll")                                                              \
    for (int kk_ = 0; kk_ < 2; ++kk_) {                                            \
        bf16x8 af_[4], bv_[2];                                                     \
        _Pragma("unroll")                                                          \
        for (int mt_ = 0; mt_ < 4; ++mt_) {                                        \
            int row_ = mq * 64 + mt_ * 16 + col;                                   \
            int slot_ = (kk_ * 4 + quad) ^ (row_ & 7);                             \
            af_[mt_] = *(const bf16x8*)(&As2[row_ * 64 + slot_ * 8]);              \
        }                                                                          \
        _Pragma("unroll")                                                          \
        for (int nt_ = 0; nt_ < 2; ++nt_) {                                        \
            int row_ = nq * 32 + nt_ * 16 + col;                                   \
            int slot_ = (kk_ * 4 + quad) ^ (row_ & 7);                             \
            bv_[nt_] = *(const bf16x8*)(&Bs2[row_ * 64 + slot_ * 8]);              \
        }                                                                          \
        _Pragma("unroll")                                                          \
        for (int mt_ = 0; mt_ < 4; ++mt_)                                          \
            _Pragma("unroll")                                                      \
            for (int nt_ = 0; nt_ < 2; ++nt_)                                      \
                ACC[mt_][nt_] = __builtin_amdgcn_mfma_f32_16x16x32_bf16(           \
                    af_[mt_], bv_[nt_], ACC[mt_][nt_], 0, 0, 0);                   \
    }                                                                              \
} while (0)

#define GEPI(ACC, M0, YH) do {                                                     \
    _Pragma("unroll")                                                              \
    for (int mt_ = 0; mt_ < 4; ++mt_)                                              \
        _Pragma("unroll")                                                          \
        for (int nt_ = 0; nt_ < 2; ++nt_) {                                        \
            int m_ = (M0) + mq * 64 + mt_ * 16 + quad * 4;                         \
            int idx_ = nq * 32 + nt_ * 16 + col;                                   \
            int yy_ = (YH) * 2 + (idx_ >> 6), wl_ = idx_ & 63;                     \
            _Pragma("unroll")                                                      \
            for (int r_ = 0; r_ < 4; ++r_)                                         \
                ic_store16(&Hring[(((size_t)(m_ + r_) * 16 + b) * 8 +              \
                                   (yy_ & 7)) * 64 + wl_],                         \
                           (bf16)ACC[mt_][nt_][r_]);                               \
        }                                                                          \
} while (0)

#define HPREF(YY) do {                                                             \
    int slot_ = (YY) & 7;                                                          \
    _Pragma("unroll")                                                              \
    for (int i_ = 0; i_ < 2; ++i_) {                                               \
        int w_ = (wn * 2 + i_) * 16 + col;                                         \
        _Pragma("unroll")                                                          \
        for (int r_ = 0; r_ < 4; ++r_)                                             \
            hadd[i_][r_] = ic_load_bf16(&Hring[(((size_t)(r_ * FEAT + fmine) * 16  \
                                                 + b) * 8 + slot_) * 64 + w_]);    \
    }                                                                              \
} while (0)

    f32x4 accg[4][2];
    float hadd[2][4];

    // ---- prologue: tile 0 full (12 K-iters) + epilogue + flag ----
    {
        const int t0 = j;
        const int m0_ = (t0 % 6) * 128, yh_ = t0 / 6;
        const size_t p0_ = ((size_t)b * 64 + yh_ * 2) * 64;
        #pragma unroll
        for (int mt_ = 0; mt_ < 4; ++mt_)
            for (int nt_ = 0; nt_ < 2; ++nt_) accg[mt_][nt_] = f32x4{0.f, 0.f, 0.f, 0.f};
        for (int ki = 0; ki < 12; ++ki) {
            GSTAGE(m0_, p0_, ki * 64);
            __syncthreads();
            GMFMA(accg);
            __syncthreads();
        }
        GEPI(accg, m0_, yh_);
        __syncthreads();                         // drain sc1 stores (all waves)
        if (tid == 0) ic_store32(&gflags[j], 1u);
        // wait for all 12 blocks' tile 0 (covers yh=0 => Hring row 0)
        while (true) {
            unsigned v = (lane < 12) ? ic_load32(&gflags[lane]) : 1u;
            if (__ballot(v >= 1u) == ~0ull) break;
            __builtin_amdgcn_s_sleep(1);
        }
        asm volatile("" ::: "memory");
        HPREF(0);                                // gate biases for row 0
    }

    for (int y = 0; y < 64; ++y) {
        // ---- gates GEMM: s = i2s-bias + Ws2s * im2col(h(y-1)) ----
        f32x4 acc[2] = {};
        for (int kc = 0; kc < 18; ++kc) {
            int k0 = kc * 32 + quad * 8;
            int t = k0 / FEAT, f = k0 % FEAT;
            #pragma unroll
            for (int i = 0; i < 2; ++i) {
                int w = (wn * 2 + i) * 16 + col;
                bf16x8 bfr = *(const bf16x8*)(&hlds[(w + t) * 200 + f]);
                acc[i] = __builtin_amdgcn_mfma_f32_16x16x32_bf16(Ag[kc], bfr, acc[i], 0, 0, 0);
            }
        }
        // ---- LSTM update -> hnew ----
        #pragma unroll
        for (int i = 0; i < 2; ++i) {
            int w = (wn * 2 + i) * 16 + col;
            float so = acc[i][0] + hadd[i][0];
            float sf = acc[i][1] + hadd[i][1];
            float si = acc[i][2] + hadd[i][2];
            float sg = acc[i][3] + hadd[i][3];
            float go = sigm_fast(so);
            float gf = sigm_fast(sf);
            float gi = sigm_fast(si);
            float gg = sigm_fast(sg);
            float cc = gf * cstate[i] + gi * gg;
            cstate[i] = cc;
            hnew[w * 20 + lf] = (bf16)(go * tanh_fast(cc));
        }
        __syncthreads();   // S1: hnew complete

        // ---- publish own 16f slice of h(y) -> hg[y%3][b] ----
        if (tid < 256) {
            bf16* dst = hg + ((size_t)(y % 3) * 16 + b) * (66 * 192);
            int w = tid >> 2, fo = (tid & 3) * 4;
            u64 v = *(const u64*)(&hnew[w * 20 + fo]);
            ic_store64((u64*)(dst + (size_t)(w + 1) * 192 + 16 * j + fo), v);
        }
        __syncthreads();   // S2: vmcnt(0) drain => publishes visible at IC
        if (tid == 0) ic_store32(&myflags[j], (unsigned)(y + 1));

        // ---- i2s GEMM chunk: tile n = y/4+1, 3 K-iters (spin shadow) ----
        if (y < 60) {
            const int n_ = (y >> 2) + 1;
            const int t_ = j + 12 * n_;
            const int m0_ = (t_ % 6) * 128, yh_ = t_ / 6;
            const size_t p0_ = ((size_t)b * 64 + yh_ * 2) * 64;
            const int ph_ = y & 3;
            if (ph_ == 0) {
                #pragma unroll
                for (int mt_ = 0; mt_ < 4; ++mt_)
                    for (int nt_ = 0; nt_ < 2; ++nt_) accg[mt_][nt_] = f32x4{0.f, 0.f, 0.f, 0.f};
            }
            for (int ki = ph_ * 3; ki < ph_ * 3 + 3; ++ki) {
                GSTAGE(m0_, p0_, ki * 64);
                __syncthreads();
                GMFMA(accg);
                __syncthreads();
            }
            if (ph_ == 3) {
                GEPI(accg, m0_, yh_);
                __syncthreads();                 // drain tile stores
                if (tid == 0) ic_store32(&gflags[j], (unsigned)(n_ + 1));
            }
        }

        // ---- gated prefetch of gate biases for row y+1 ----
        if (y < 63) {
            const int yhreq = (y + 1) >> 1;
            unsigned tgt = 0;
            if (lane < 12) {
                int o = (lane >= 6) ? 1 : 0;
                tgt = (yhreq >= o) ? (unsigned)(((yhreq - o) >> 1) + 1) : 0u;
            }
            while (true) {
                unsigned v = (lane < 12) ? ic_load32(&gflags[lane]) : 0u;
                if (__ballot(v >= tgt) == ~0ull) break;
                __builtin_amdgcn_s_sleep(1);
            }
            asm volatile("" ::: "memory");
            HPREF(y + 1);
        }

        // ---- skip GEMM + residual out for row y-1 (spin shadow) ----
        if (y > 0) {
            const int ym = y - 1;
            f32x4 acc2 = {};
            int wsk = ntk * 16 + col;
            for (int kc = 0; kc < 6; ++kc) {
                bf16x8 bfr = *(const bf16x8*)(&hlds[(wsk + 1) * 200 + kc * 32 + quad * 8]);
                acc2 = __builtin_amdgcn_mfma_f32_16x16x32_bf16(Ak[kc], bfr, acc2, 0, 0, 0);
            }
            for (int r = 0; r < 4; ++r) {
                int co = 32 * j + mtk * 16 + quad * 4 + r;
                size_t xi = ((size_t)(b * CINCH + co) * HH + ym) * WW + wsk;
                out[xi] = x[xi] + b_skip[co] + acc2[r];
            }
        }
        __syncthreads();   // S3: hlds reads done before restage

        // ---- h-spin: all 12 h-flags >= y+1 ----
        {
            const unsigned tgt = (unsigned)(y + 1);
            while (true) {
                unsigned v = (lane < 12) ? ic_load32(&myflags[lane]) : tgt;
                if (__ballot(v >= tgt) == ~0ull) break;
                __builtin_amdgcn_s_sleep(1);
            }
            asm volatile("" ::: "memory");
        }

        // ---- stage h(y) -> hlds ----
        {
            const u64* src = (const u64*)(hg + ((size_t)(y % 3) * 16 + b) * (66 * 192));
            #pragma unroll
            for (int it = 0; it < 7; ++it) {
                int c = it * SCANT + tid;
                if (c < 66 * 48) {
                    u64 v = ic_load64(src + c);
                    int w = c / 48, fc = c % 48;
                    *(u64*)(&hlds[w * 200 + fc * 4]) = v;
                }
            }
        }
        __syncthreads();   // S4: stage visible
    }

    // ---- epilogue: skip GEMM + residual for row 63 ----
    {
        f32x4 acc2 = {};
        int wsk = ntk * 16 + col;
        for (int kc = 0; kc < 6; ++kc) {
            bf16x8 bfr = *(const bf16x8*)(&hlds[(wsk + 1) * 200 + kc * 32 + quad * 8]);
            acc2 = __builtin_amdgcn_mfma_f32_16x16x32_bf16(Ak[kc], bfr, acc2, 0, 0, 0);
        }
        for (int r = 0; r < 4; ++r) {
            int co = 32 * j + mtk * 16 + quad * 4 + r;
            size_t xi = ((size_t)(b * CINCH + co) * HH + 63) * WW + wsk;
            out[xi] = x[xi] + b_skip[co] + acc2[r];
        }
    }

#undef GSTAGE
#undef GMFMA
#undef GEPI
#undef HPREF
}

// ============================================================
extern "C" void kernel_launch(void* const* d_in, const int* in_sizes, int n_in,
                              void* d_out, int out_size, void* d_ws, size_t ws_size,
                              hipStream_t stream) {
    const float* x      = (const float*)d_in[0];
    const float* w_i2s  = (const float*)d_in[1];
    const float* w_s2s  = (const float*)d_in[2];
    const float* w_skip = (const float*)d_in[3];
    const float* b_skip = (const float*)d_in[4];
    float* out = (float*)d_out;

    char* ws = (char*)d_ws;
    bf16* Xc    = (bf16*)ws;
    size_t off  = (size_t)NP * CINCH * 2;                // 50,331,648
    bf16* WpA   = (bf16*)(ws + off); off += (size_t)CGATE * KI2S * 2;
    bf16* WpS   = (bf16*)(ws + off); off += (size_t)CGATE * KS2S * 2;
    bf16* WpK   = (bf16*)(ws + off); off += (size_t)CINCH * FEAT * 2;
    bf16* hg    = (bf16*)(ws + off); off += (size_t)3 * 16 * 66 * 192 * 2;
    bf16* Hring = (bf16*)(ws + off); off += (size_t)CGATE * 16 * 8 * 64 * 2;  // 12.6 MB
    unsigned* cnt = (unsigned*)(ws + off); off += 4096;  // 1024 u32
    bf16* zp    = (bf16*)(ws + off); off += 1024;        // zero page

    pack_weights<<<256, 256, 0, stream>>>(w_i2s, w_s2s, w_skip, WpA, WpS, WpK, zp);
    pack_xc<<<BATCH * HH, 256, 0, stream>>>(x, Xc);

    void* args[] = { (void*)&WpA, (void*)&WpS, (void*)&WpK, (void*)&Xc, (void*)&zp,
                     (void*)&x, (void*)&b_skip, (void*)&out, (void*)&hg, (void*)&cnt,
                     (void*)&Hring };
    hipLaunchCooperativeKernel((const void*)scan_kernel, dim3(NBLK), dim3(SCANT),
                               args, 0, stream);
}

// Round 10
// 748.953 us; speedup vs baseline: 1.0304x; 1.0304x over previous
//
#include <hip/hip_runtime.h>
#include <hip/hip_cooperative_groups.h>
#include <cmath>

// ---------------- problem constants ----------------
#define FEAT  192
#define CINCH 384          // CIN
#define CGATE 768
#define BATCH 16
#define HH    64
#define WW    64
#define NP    (BATCH*HH*WW)   // 65536 flattened (b,y,w)
#define KI2S  768             // 384 ic * 2 live taps
#define KS2S  576             // 192 feat * 3 taps
#define NSCAN 192             // scan blocks: 16 batches x 12 f-chunks
#define NPROD 64              // producer blocks: 16 batches x 4 slots (3 j each)
#define NBLK  (NSCAN+NPROD)   // 256 total: co-resident at ANY occupancy >= 1/CU
#define SCANT 512             // threads: 8 waves
#define RING  16              // Hring rows per batch

using bf16   = __bf16;
using bf16x8 = __attribute__((ext_vector_type(8))) __bf16;
using bf16x4 = __attribute__((ext_vector_type(4))) __bf16;
using f32x4  = __attribute__((ext_vector_type(4))) float;
typedef unsigned long long u64;

// ---------------------------------------------------------------
// IC-coherent accessors (verified R1..R8): relaxed agent-scope atomics
// -> plain global_load/store sc0/sc1, coherent at Infinity Cache.
// Visibility: sc1 store completion (vmcnt==0 via __syncthreads) => at IC.
// ---------------------------------------------------------------
__device__ __forceinline__ void ic_store64(u64* p, u64 v) {
    __hip_atomic_store(p, v, __ATOMIC_RELAXED, __HIP_MEMORY_SCOPE_AGENT);
}
__device__ __forceinline__ u64 ic_load64(const u64* p) {
    return __hip_atomic_load(p, __ATOMIC_RELAXED, __HIP_MEMORY_SCOPE_AGENT);
}
__device__ __forceinline__ void ic_store32(unsigned* p, unsigned v) {
    __hip_atomic_store(p, v, __ATOMIC_RELAXED, __HIP_MEMORY_SCOPE_AGENT);
}
__device__ __forceinline__ unsigned ic_load32(const unsigned* p) {
    return __hip_atomic_load(p, __ATOMIC_RELAXED, __HIP_MEMORY_SCOPE_AGENT);
}
__device__ __forceinline__ void ic_store16(bf16* p, bf16 h) {
    union { bf16 h; unsigned short u; } cv; cv.h = h;
    __hip_atomic_store((unsigned short*)p, cv.u, __ATOMIC_RELAXED, __HIP_MEMORY_SCOPE_AGENT);
}
__device__ __forceinline__ float ic_load_bf16(const bf16* p) {
    union { unsigned short u; bf16 h; } cv;
    cv.u = __hip_atomic_load((const unsigned short*)p, __ATOMIC_RELAXED, __HIP_MEMORY_SCOPE_AGENT);
    return (float)cv.h;
}

__device__ __forceinline__ float sigm_fast(float v) {
    return __builtin_amdgcn_rcpf(1.f + __expf(-v));
}
__device__ __forceinline__ float tanh_fast(float v) {
    return 1.f - 2.f * __builtin_amdgcn_rcpf(1.f + __expf(2.f * v));
}

// ============================================================
// Pack weights (verified) + zero page.
// ============================================================
__global__ void pack_weights(const float* __restrict__ wi, const float* __restrict__ ws,
                             const float* __restrict__ wk,
                             bf16* __restrict__ WpA, bf16* __restrict__ WpS,
                             bf16* __restrict__ WpK, bf16* __restrict__ zp) {
    int tid = blockIdx.x * 256 + threadIdx.x;
    int stride = gridDim.x * 256;
    for (int idx = tid; idx < 512; idx += stride) zp[idx] = (bf16)0.f;
    for (int idx = tid; idx < CGATE * KI2S; idx += stride) {
        int cp = idx / KI2S, k = idx % KI2S;
        int q = cp / 192, r = cp % 192, g = r / 64, f = r % 64;
        int c = g * 256 + q * 64 + f;             // original (pre-shuffle) out channel
        float v;
        if (k < CINCH) {
            v = wi[(c * CINCH + k) * 3 + 0];      // tap0 (pairs with x[w-1])
        } else {
            int ic = k - CINCH;                   // tap1 (center, causal mask)
            v = (g >= ic / 128) ? wi[(c * CINCH + ic) * 3 + 1] : 0.f;
        }
        WpA[idx] = (bf16)v;
    }
    for (int idx = tid; idx < CGATE * KS2S; idx += stride) {
        int oc = idx / KS2S, k = idx % KS2S;
        int t = k / FEAT, f = k % FEAT;
        WpS[idx] = (bf16)ws[(oc * FEAT + f) * 3 + t];
    }
    for (int idx = tid; idx < CINCH * FEAT; idx += stride) {
        int co = idx / FEAT, f = idx % FEAT;
        WpK[idx] = (co / 128 >= f / 64) ? (bf16)wk[idx] : (bf16)0.f;
    }
}

// ============================================================
// Pack x (fp32 NCHW) -> Xc bf16 [p=(b,y,w)][ic 0..384) (verified R8)
// ============================================================
__global__ void pack_xc(const float* __restrict__ x, bf16* __restrict__ Xc) {
    __shared__ float tile[64][65];
    int b = blockIdx.x >> 6, y = blockIdx.x & 63;
    const float* xb = x + ((size_t)b * CINCH * HH + y) * WW;
    bf16* Xrow = Xc + (size_t)((b * HH + y) * WW) * CINCH;
    for (int ic0 = 0; ic0 < CINCH; ic0 += 64) {
        for (int rep = 0; rep < 16; ++rep) {
            int idx = rep * 256 + threadIdx.x;
            int i = idx >> 6, w = idx & 63;
            tile[i][w] = xb[(size_t)(ic0 + i) * (HH * WW) + w];
        }
        __syncthreads();
        for (int rep = 0; rep < 16; ++rep) {
            int idx = rep * 256 + threadIdx.x;
            int w = idx >> 6, i = idx & 63;
            Xrow[(size_t)w * CINCH + ic0 + i] = (bf16)tile[i][w];
        }
        __syncthreads();
    }
}

// ============================================================
// Producer/consumer cooperative kernel, 256 blocks x 512 threads.
//  - blocks 0..191   scan: R7-verified recurrence + R8-verified HPREF.
//  - blocks 192..255 producers: 4/batch, 3 j-slots each (j = p, p+4, p+8),
//    48 tiles, n-outer order. Double-buffered K-loop with counted
//    vmcnt(4) + raw s_barrier (T3/T4): stage(k+1) in flight under MFMA(k).
// LDS: 64KB static union (producer 2x(A16K+B16K); scan hlds+hnew 29K).
// ============================================================
__global__ __launch_bounds__(SCANT, 2) void scan_kernel(
    const bf16* __restrict__ WpA,    // [768][768] i2s weights
    const bf16* __restrict__ Ws2s,   // [768][576]
    const bf16* __restrict__ Wskip,  // [384][192]
    const bf16* __restrict__ Xc,     // [65536][384]
    const bf16* __restrict__ zp,     // 1KB zero page
    const float* __restrict__ x,
    const float* __restrict__ b_skip,
    float* __restrict__ out,
    bf16* __restrict__ hg,           // [3][16][66*192]
    unsigned* __restrict__ cnt,      // [0..511] h-flags, [512..1023] g-flags
    bf16* __restrict__ Hring) {      // [768][16][RING][64]
    cooperative_groups::grid_group grid = cooperative_groups::this_grid();
    __shared__ __align__(16) bf16 smem[32768];      // 64 KB union
    bf16* const hlds = smem;                        // scan: [66*200]
    bf16* const hnew = smem + 13200;                // scan: [64*20]
    const int bid = blockIdx.x;
    const bool isScan = bid < NSCAN;
    const int tid = threadIdx.x, lane = tid & 63, wid = tid >> 6;
    const int quad = lane >> 4, col = lane & 15;
    const int mq = wid & 1, nq = wid >> 1;      // producer GEMM wave roles

    // ---- init: zero hg (all blocks) + flags (scan blocks) ----
    {
        const int total = 3 * 16 * 66 * 192 / 2;   // dwords
        for (int i = bid * SCANT + tid; i < total; i += NBLK * SCANT)
            ((unsigned*)hg)[i] = 0u;
        if (isScan) {
            if (tid < 32) cnt[(bid % 16) * 32 + tid] = 0u;
            if (tid >= 64 && tid < 96) cnt[512 + (bid % 16) * 32 + (tid - 64)] = 0u;
        }
    }
    grid.sync();   // init visibility

// ---- i2s GEMM macros (R8-verified addressing; BUF selects dbuf half) ----
#define GSTAGE(BUF, M0, P0, K0) do {                                               \
    bf16* const dAb_ = smem + (BUF) * 8192;                                        \
    bf16* const dBb_ = smem + 16384 + (BUF) * 8192;                                \
    _Pragma("unroll")                                                              \
    for (int r_ = 0; r_ < 2; ++r_) {                                               \
        int L_ = r_ * 512 + tid;                                                   \
        int row_ = L_ >> 3, slot_ = L_ & 7;                                        \
        int c_ = slot_ ^ (row_ & 7);                                               \
        const bf16* srcA = &WpA[(size_t)((M0) + row_) * KI2S + (K0) + c_ * 8];     \
        const bf16* srcB;                                                          \
        if ((K0) < 384) {                                                          \
            srcB = ((row_ & 63) == 0) ? (zp + c_ * 8)                              \
                 : &Xc[(size_t)((P0) + row_ - 1) * CINCH + (K0) + c_ * 8];         \
        } else {                                                                   \
            srcB = &Xc[(size_t)((P0) + row_) * CINCH + (K0) - 384 + c_ * 8];       \
        }                                                                          \
        __builtin_amdgcn_global_load_lds(                                          \
            (const __attribute__((address_space(1))) void*)srcA,                   \
            (__attribute__((address_space(3))) void*)(dAb_ + (size_t)(r_ * 512 +   \
                wid * 64) * 8), 16, 0, 0);                                         \
        __builtin_amdgcn_global_load_lds(                                          \
            (const __attribute__((address_space(1))) void*)srcB,                   \
            (__attribute__((address_space(3))) void*)(dBb_ + (size_t)(r_ * 512 +   \
                wid * 64) * 8), 16, 0, 0);                                         \
    }                                                                              \
} while (0)

#define GMFMA(ACC, BUF) do {                                                       \
    const bf16* const sAb_ = smem + (BUF) * 8192;                                  \
    const bf16* const sBb_ = smem + 16384 + (BUF) * 8192;                          \
    _Pragma("unroll")                                                              \
    for (int kk_ = 0; kk_ < 2; ++kk_) {                                            \
        bf16x8 af_[4], bv_[2];                                                     \
        _Pragma("unroll")                                                          \
        for (int mt_ = 0; mt_ < 4; ++mt_) {                                        \
            int row_ = mq * 64 + mt_ * 16 + col;                                   \
            int slot_ = (kk_ * 4 + quad) ^ (row_ & 7);                             \
            af_[mt_] = *(const bf16x8*)(&sAb_[row_ * 64 + slot_ * 8]);             \
        }                                                                          \
        _Pragma("unroll")                                                          \
        for (int nt_ = 0; nt_ < 2; ++nt_) {                                        \
            int row_ = nq * 32 + nt_ * 16 + col;                                   \
            int slot_ = (kk_ * 4 + quad) ^ (row_ & 7);                             \
            bv_[nt_] = *(const bf16x8*)(&sBb_[row_ * 64 + slot_ * 8]);             \
        }                                                                          \
        _Pragma("unroll")                                                          \
        for (int mt_ = 0; mt_ < 4; ++mt_)                                          \
            _Pragma("unroll")                                                      \
            for (int nt_ = 0; nt_ < 2; ++nt_)                                      \
                ACC[mt_][nt_] = __builtin_amdgcn_mfma_f32_16x16x32_bf16(           \
                    af_[mt_], bv_[nt_], ACC[mt_][nt_], 0, 0, 0);                   \
    }                                                                              \
} while (0)

#define GEPI(ACC, M0, YH, BB) do {                                                 \
    _Pragma("unroll")                                                              \
    for (int mt_ = 0; mt_ < 4; ++mt_)                                              \
        _Pragma("unroll")                                                          \
        for (int nt_ = 0; nt_ < 2; ++nt_) {                                        \
            int m_ = (M0) + mq * 64 + mt_ * 16 + quad * 4;                         \
            int idx_ = nq * 32 + nt_ * 16 + col;                                   \
            int yy_ = (YH) * 2 + (idx_ >> 6), wl_ = idx_ & 63;                     \
            _Pragma("unroll")                                                      \
            for (int r_ = 0; r_ < 4; ++r_)                                         \
                ic_store16(&Hring[(((size_t)(m_ + r_) * 16 + (BB)) * RING +        \
                                   (yy_ & (RING - 1))) * 64 + wl_],                \
                           (bf16)ACC[mt_][nt_][r_]);                               \
        }                                                                          \
} while (0)

#define HPREF(YY) do {                                                             \
    int slot_ = (YY) & (RING - 1);                                                 \
    _Pragma("unroll")                                                              \
    for (int i_ = 0; i_ < 2; ++i_) {                                               \
        int w_ = (wn * 2 + i_) * 16 + col;                                         \
        _Pragma("unroll")                                                          \
        for (int r_ = 0; r_ < 4; ++r_)                                             \
            hadd[i_][r_] = ic_load_bf16(&Hring[(((size_t)(r_ * FEAT + fmine) * 16  \
                                                 + b) * RING + slot_) * 64 + w_]); \
    }                                                                              \
} while (0)

    // ================= PRODUCER ROLE =================
    if (!isScan) {
        const int pid = bid - NSCAN;            // 0..63
        const int pb = pid & 15;                // batch
        const int pslot = pid >> 4;             // 0..3
        unsigned* phf = cnt + pb * 32;          // h flags of my batch
        unsigned* pgf = cnt + 512 + pb * 32;    // g flags of my batch
        for (int n = 0; n < 16; ++n) {
            for (int q3 = 0; q3 < 3; ++q3) {
                const int jj = pslot + q3 * 4;  // 3 j-slots per producer
                const int t_ = jj + 12 * n;
                const int m0_ = (t_ % 6) * 128, yh_ = t_ / 6;
                const size_t p0_ = ((size_t)pb * 64 + yh_ * 2) * 64;
                // ring-reuse throttle (audited R9): need hflags >= 2yh-(RING-2)
                const int needi = 2 * yh_ - (RING - 2);
                if (needi > 0) {
                    const unsigned need = (unsigned)needi;
                    while (true) {
                        unsigned v = (lane < 12) ? ic_load32(&phf[lane]) : need;
                        if (__ballot(v >= need) == ~0ull) break;
                        __builtin_amdgcn_s_sleep(8);
                    }
                    asm volatile("" ::: "memory");
                }
                f32x4 accg[4][2];
                #pragma unroll
                for (int mt_ = 0; mt_ < 4; ++mt_)
                    for (int nt_ = 0; nt_ < 2; ++nt_)
                        accg[mt_][nt_] = f32x4{0.f, 0.f, 0.f, 0.f};
                // pipelined 12 K-iters: stage(k+1) in flight under MFMA(k).
                // Hazards: vmcnt(4) retires current buffer's 4 loads/thread;
                // lgkmcnt(0)+barrier retires reads of a buffer before restage.
                GSTAGE(0, m0_, p0_, 0);
                #pragma unroll 1
                for (int ki = 0; ki < 12; ++ki) {
                    if (ki < 11) {
                        GSTAGE((ki + 1) & 1, m0_, p0_, (ki + 1) * 64);
                        asm volatile("s_waitcnt vmcnt(4)" ::: "memory");
                    } else {
                        asm volatile("s_waitcnt vmcnt(0)" ::: "memory");
                    }
                    __builtin_amdgcn_sched_barrier(0);
                    __builtin_amdgcn_s_barrier();
                    GMFMA(accg, ki & 1);
                    asm volatile("s_waitcnt lgkmcnt(0)" ::: "memory");
                    __builtin_amdgcn_sched_barrier(0);
                    __builtin_amdgcn_s_barrier();
                }
                GEPI(accg, m0_, yh_, pb);
                __syncthreads();                 // vmcnt(0): tile at IC
                if (tid == 0) ic_store32(&pgf[jj], (unsigned)(n + 1));
            }
        }
        return;                                  // producers done; CUs free
    }

    // ================= SCAN ROLE (R7-verified loop + R8-verified HPREF) ====
    const int b = (bid & 7) * 2 + (bid / 96);   // same-batch blocks share bid%8
    const int j = (bid >> 3) % 12;
    const int wh = wid & 3;                     // h-GEMM m-slice role
    const int wn = wid >> 2;                    // h-GEMM n-half
    bf16x8 Ag[18];
    {
        int f = 16 * j + wh * 4 + (col >> 2), q = col & 3;
        const bf16* Arow = Ws2s + (size_t)(q * 192 + f) * KS2S + quad * 8;
        for (int kc = 0; kc < 18; ++kc) Ag[kc] = *(const bf16x8*)(Arow + kc * 32);
    }
    bf16x8 Ak[6];
    const int mtk = wid & 1, ntk = wid >> 1;    // skip: co-half x w-quarter
    {
        int co = 32 * j + mtk * 16 + col;
        const bf16* Krow = Wskip + (size_t)co * FEAT + quad * 8;
        for (int kc = 0; kc < 6; ++kc) Ak[kc] = *(const bf16x8*)(Krow + kc * 32);
    }
    const int fmine = 16 * j + wh * 4 + quad;
    const int lf = wh * 4 + quad;               // local feature 0..15
    float cstate[2] = {0.f, 0.f};
    float hadd[2][4];
    unsigned* hflags = cnt + b * 32;
    unsigned* gflags = cnt + 512 + b * 32;
    for (int i = tid; i < 66 * 100; i += SCANT) ((unsigned*)hlds)[i] = 0u;  // h(-1)=0
    __syncthreads();

    // prologue: wait tile 0 from all 12 j-slots, HPREF(0)
    {
        while (true) {
            unsigned v = (lane < 12) ? ic_load32(&gflags[lane]) : 1u;
            if (__ballot(v >= 1u) == ~0ull) break;
            __builtin_amdgcn_s_sleep(1);
        }
        asm volatile("" ::: "memory");
        HPREF(0);
    }

    for (int y = 0; y < 64; ++y) {
        // ---- gates GEMM: s = i2s-bias + Ws2s * im2col(h(y-1)) ----
        f32x4 acc[2] = {};
        for (int kc = 0; kc < 18; ++kc) {
            int k0 = kc * 32 + quad * 8;
            int t = k0 / FEAT, f = k0 % FEAT;
            #pragma unroll
            for (int i = 0; i < 2; ++i) {
                int w = (wn * 2 + i) * 16 + col;
                bf16x8 bfr = *(const bf16x8*)(&hlds[(w + t) * 200 + f]);
                acc[i] = __builtin_amdgcn_mfma_f32_16x16x32_bf16(Ag[kc], bfr, acc[i], 0, 0, 0);
            }
        }
        // ---- LSTM update -> hnew ----
        #pragma unroll
        for (int i = 0; i < 2; ++i) {
            int w = (wn * 2 + i) * 16 + col;
            float so = acc[i][0] + hadd[i][0];
            float sf = acc[i][1] + hadd[i][1];
            float si = acc[i][2] + hadd[i][2];
            float sg = acc[i][3] + hadd[i][3];
            float go = sigm_fast(so);
            float gf = sigm_fast(sf);
            float gi = sigm_fast(si);
            float gg = sigm_fast(sg);
            float cc = gf * cstate[i] + gi * gg;
            cstate[i] = cc;
            hnew[w * 20 + lf] = (bf16)(go * tanh_fast(cc));
        }
        __syncthreads();   // S1: hnew complete

        // ---- publish own 16f slice of h(y) -> hg[y%3][b] ----
        if (tid < 256) {
            bf16* dst = hg + ((size_t)(y % 3) * 16 + b) * (66 * 192);
            int w = tid >> 2, fo = (tid & 3) * 4;
            u64 v = *(const u64*)(&hnew[w * 20 + fo]);
            ic_store64((u64*)(dst + (size_t)(w + 1) * 192 + 16 * j + fo), v);
        }
        __syncthreads();   // S2: vmcnt(0) => publishes at IC
        if (tid == 0) ic_store32(&hflags[j], (unsigned)(y + 1));

        // ---- gated prefetch of gate biases for row y+1 (verified R8) ----
        if (y < 63) {
            const int yhreq = (y + 1) >> 1;
            unsigned tgt = 0;
            if (lane < 12) {
                int o = (lane >= 6) ? 1 : 0;
                tgt = (yhreq >= o) ? (unsigned)(((yhreq - o) >> 1) + 1) : 0u;
            }
            while (true) {
                unsigned v = (lane < 12) ? ic_load32(&gflags[lane]) : 0u;
                if (__ballot(v >= tgt) == ~0ull) break;
                __builtin_amdgcn_s_sleep(1);
            }
            asm volatile("" ::: "memory");
            HPREF(y + 1);
        }

        // ---- skip GEMM + residual out for row y-1 (spin shadow) ----
        if (y > 0) {
            const int ym = y - 1;
            f32x4 acc2 = {};
            int wsk = ntk * 16 + col;
            for (int kc = 0; kc < 6; ++kc) {
                bf16x8 bfr = *(const bf16x8*)(&hlds[(wsk + 1) * 200 + kc * 32 + quad * 8]);
                acc2 = __builtin_amdgcn_mfma_f32_16x16x32_bf16(Ak[kc], bfr, acc2, 0, 0, 0);
            }
            for (int r = 0; r < 4; ++r) {
                int co = 32 * j + mtk * 16 + quad * 4 + r;
                size_t xi = ((size_t)(b * CINCH + co) * HH + ym) * WW + wsk;
                out[xi] = x[xi] + b_skip[co] + acc2[r];
            }
        }
        __syncthreads();   // S3: hlds reads done before restage

        // ---- h-spin: all 12 h-flags >= y+1 ----
        {
            const unsigned tgt = (unsigned)(y + 1);
            while (true) {
                unsigned v = (lane < 12) ? ic_load32(&hflags[lane]) : tgt;
                if (__ballot(v >= tgt) == ~0ull) break;
                __builtin_amdgcn_s_sleep(1);
            }
            asm volatile("" ::: "memory");
        }

        // ---- stage h(y) -> hlds ----
        {
            const u64* src = (const u64*)(hg + ((size_t)(y % 3) * 16 + b) * (66 * 192));
            #pragma unroll
            for (int it = 0; it < 7; ++it) {
                int c = it * SCANT + tid;
                if (c < 66 * 48) {
                    u64 v = ic_load64(src + c);
                    int w = c / 48, fc = c % 48;
                    *(u64*)(&hlds[w * 200 + fc * 4]) = v;
                }
            }
        }
        __syncthreads();   // S4: stage visible
    }

    // ---- epilogue: skip GEMM + residual for row 63 ----
    {
        f32x4 acc2 = {};
        int wsk = ntk * 16 + col;
        for (int kc = 0; kc < 6; ++kc) {
            bf16x8 bfr = *(const bf16x8*)(&hlds[(wsk + 1) * 200 + kc * 32 + quad * 8]);
            acc2 = __builtin_amdgcn_mfma_f32_16x16x32_bf16(Ak[kc], bfr, acc2, 0, 0, 0);
        }
        for (int r = 0; r < 4; ++r) {
            int co = 32 * j + mtk * 16 + quad * 4 + r;
            size_t xi = ((size_t)(b * CINCH + co) * HH + 63) * WW + wsk;
            out[xi] = x[xi] + b_skip[co] + acc2[r];
        }
    }

#undef GSTAGE
#undef GMFMA
#undef GEPI
#undef HPREF
}

// ============================================================
extern "C" void kernel_launch(void* const* d_in, const int* in_sizes, int n_in,
                              void* d_out, int out_size, void* d_ws, size_t ws_size,
                              hipStream_t stream) {
    const float* x      = (const float*)d_in[0];
    const float* w_i2s  = (const float*)d_in[1];
    const float* w_s2s  = (const float*)d_in[2];
    const float* w_skip = (const float*)d_in[3];
    const float* b_skip = (const float*)d_in[4];
    float* out = (float*)d_out;

    char* ws = (char*)d_ws;
    bf16* Xc    = (bf16*)ws;
    size_t off  = (size_t)NP * CINCH * 2;                // 50,331,648
    bf16* WpA   = (bf16*)(ws + off); off += (size_t)CGATE * KI2S * 2;
    bf16* WpS   = (bf16*)(ws + off); off += (size_t)CGATE * KS2S * 2;
    bf16* WpK   = (bf16*)(ws + off); off += (size_t)CINCH * FEAT * 2;
    bf16* hg    = (bf16*)(ws + off); off += (size_t)3 * 16 * 66 * 192 * 2;
    bf16* Hring = (bf16*)(ws + off); off += (size_t)CGATE * 16 * RING * 64 * 2;  // 25.2 MB
    unsigned* cnt = (unsigned*)(ws + off); off += 4096;  // 1024 u32
    bf16* zp    = (bf16*)(ws + off); off += 1024;        // zero page

    pack_weights<<<256, 256, 0, stream>>>(w_i2s, w_s2s, w_skip, WpA, WpS, WpK, zp);
    pack_xc<<<BATCH * HH, 256, 0, stream>>>(x, Xc);

    void* args[] = { (void*)&WpA, (void*)&WpS, (void*)&WpK, (void*)&Xc, (void*)&zp,
                     (void*)&x, (void*)&b_skip, (void*)&out, (void*)&hg, (void*)&cnt,
                     (void*)&Hring };
    hipLaunchCooperativeKernel((const void*)scan_kernel, dim3(NBLK), dim3(SCANT),
                               args, 0, stream);
}